// Round 12
// baseline (183.087 us; speedup 1.0000x reference)
//
#include <hip/hip_runtime.h>

// Compact bilinear pooling via Gram GEMM + hash GATHER (no FFT, no fp atomics).
//   out[b,d] = sum over pairs (c1,c2) with (h1[c1]+h2[c2])%D==d of
//              s1[c1]*s2[c2]*G[b,c1,c2],  G[b] = X1_b^T X2_b (HW=196).
//
// R12: R9/R11 isolated the real floor: LDS fp-atomic scatter = ~48us
// (8.39M lane-atomics x ~3.5cyc/lane, per-lane serialized through the CU
// atomic unit). Fix: invert to gather. Counting-sort the 262144 (c1,c2)
// pairs by bucket ONCE per launch (batch-independent; int atomics at
// R4-measured ~25/cyc => ~5us/pass), gram stores flat G[b][512][512]
// (flat idx == packed entry), gather kernel sums each bucket's ~32 entries
// with plain loads (G_b 1MB L2/L3-resident, XCD-pinned per batch) and
// plain stores. parts + reduce passes eliminated.

#define NB   32
#define HW   196
#define CC   512
#define DD   8192
#define KP   224
#define NTHR 256
#define NPAIR (CC * CC)          // 262144
#define TILES_PER_B 16

typedef __attribute__((ext_vector_type(8)))  __bf16 bf8;
typedef __attribute__((ext_vector_type(16))) float  f32x16;

// ---- ws layout (bytes) ----
#define G_BYTES    ((size_t)NB * CC * CC * 4)        // 33,554,432
#define XT_ELEMS   ((size_t)NB * CC * KP)            // 3,670,016
#define XT_BYTES   (XT_ELEMS * 2)                    // 7,340,032
#define OFF_G      ((size_t)0)
#define OFF_XT1    (G_BYTES)                         // 33,554,432
#define OFF_XT2    (OFF_XT1 + XT_BYTES)              // 40,894,464
#define OFF_CNT    (OFF_XT2 + XT_BYTES)              // 48,234,496
#define OFF_CUR    (OFF_CNT + 32768)                 // 48,267,264
#define OFF_OFF    (OFF_CUR + 32768)                 // 48,300,032
#define OFF_LIST   (OFF_OFF + 32832)                 // 48,332,864
#define NEED_GATHER (OFF_LIST + (size_t)NPAIR * 4)   // 49,381,440
#define PART_BYTES ((size_t)NB * TILES_PER_B * DD * 4)
#define NEED_R5    PART_BYTES

// ---------- pass 0: x[b][k][c] fp32 -> xT[b][c][kp] bf16, signs folded ----
__global__ __launch_bounds__(NTHR) void cbp_transpose_kernel(
    const float* __restrict__ x1, const float* __restrict__ x2,
    const float* __restrict__ s1, const float* __restrict__ s2,
    __bf16* __restrict__ xT1, __bf16* __restrict__ xT2)
{
    __shared__ float T[64][65];
    const int bid = blockIdx.x;          // b*32 + ct*4 + kt
    const int b  = bid >> 5;
    const int ct = (bid >> 2) & 7;       // c tile (8 x 64)
    const int kt = bid & 3;              // k tile (4 x 64)
    const int tid = threadIdx.x;

    #pragma unroll
    for (int m = 0; m < 2; ++m) {
        const float* x   = m ? x2  : x1;
        const float* s   = m ? s2  : s1;
        __bf16*      xTo = m ? xT2 : xT1;

        #pragma unroll
        for (int p = 0; p < 4; ++p) {
            const int row  = p * 16 + (tid >> 4);      // k_local
            const int col4 = (tid & 15) * 4;           // c_local
            const int k = kt * 64 + row;
            float4 v = {0.f, 0.f, 0.f, 0.f};
            if (k < HW)
                v = *(const float4*)(x + ((size_t)(b * HW + k) * CC + ct * 64 + col4));
            T[col4 + 0][row] = v.x;
            T[col4 + 1][row] = v.y;
            T[col4 + 2][row] = v.z;
            T[col4 + 3][row] = v.w;
        }
        __syncthreads();

        const int c_l = tid >> 2;        // 0..63
        const int seg = tid & 3;         // 16 kp per seg
        const int kp0 = kt * 64 + seg * 16;
        if (kp0 < KP) {
            const float sv = s[ct * 64 + c_l];
            const size_t dstc = (size_t)(b * CC + ct * 64 + c_l) * KP;
            #pragma unroll
            for (int i2 = 0; i2 < 2; ++i2) {
                bf8 v;
                #pragma unroll
                for (int i = 0; i < 8; ++i)
                    v[i] = (__bf16)(T[c_l][seg * 16 + i2 * 8 + i] * sv);
                *(bf8*)(xTo + dstc + kp0 + i2 * 8) = v;
            }
        }
        __syncthreads();
    }
}

// ---------- pair-list build (batch-independent) ----------
__global__ __launch_bounds__(NTHR) void cbp_hist_kernel(
    const int* __restrict__ h1, const int* __restrict__ h2,
    int* __restrict__ cnt)
{
    const int gtid = blockIdx.x * NTHR + threadIdx.x;
    for (int i = gtid; i < NPAIR; i += 65536) {
        const int bkt = (h1[i >> 9] + h2[i & 511]) & (DD - 1);
        atomicAdd(&cnt[bkt], 1);
    }
}

__global__ __launch_bounds__(NTHR) void cbp_scan_kernel(
    const int* __restrict__ cnt, int* __restrict__ off)
{
    __shared__ int ls[NTHR];
    const int tid  = threadIdx.x;
    const int base = tid * 32;
    int loc[32];
    int s = 0;
    #pragma unroll
    for (int k = 0; k < 32; ++k) { loc[k] = s; s += cnt[base + k]; }
    ls[tid] = s;
    __syncthreads();
    // Hillis-Steele inclusive scan over 256 partial sums
    for (int d = 1; d < NTHR; d <<= 1) {
        int v = (tid >= d) ? ls[tid - d] : 0;
        __syncthreads();
        ls[tid] += v;
        __syncthreads();
    }
    const int blockbase = (tid == 0) ? 0 : ls[tid - 1];
    #pragma unroll
    for (int k = 0; k < 32; ++k) off[base + k] = blockbase + loc[k];
    if (tid == NTHR - 1) off[DD] = ls[NTHR - 1];
}

__global__ __launch_bounds__(NTHR) void cbp_fill_kernel(
    const int* __restrict__ h1, const int* __restrict__ h2,
    const int* __restrict__ off, int* __restrict__ cursor,
    unsigned int* __restrict__ list)
{
    const int gtid = blockIdx.x * NTHR + threadIdx.x;
    for (int i = gtid; i < NPAIR; i += 65536) {
        const int bkt = (h1[i >> 9] + h2[i & 511]) & (DD - 1);
        const int pos = off[bkt] + atomicAdd(&cursor[bkt], 1);
        list[pos] = (unsigned int)i;   // packed (c1<<9|c2) == flat G index
    }
}

// ---------- Gram MFMA, 32x32 tile per wave, flat G store ----------
__global__ __launch_bounds__(NTHR, 5) void cbp_gram_flat_kernel(
    const __bf16* __restrict__ xT1, const __bf16* __restrict__ xT2,
    float* __restrict__ G)
{
    const int bid  = blockIdx.x;                   // 0..2047
    const int swz  = (bid & 7) * 256 + (bid >> 3); // XCD chunking (bijective)
    const int tid  = threadIdx.x;
    const int wid  = tid >> 6;
    const int lane = tid & 63;
    const int lo5  = lane & 31;
    const int hi   = lane >> 5;

    const int t  = swz * 4 + wid;     // 32x32 tile id, 0..8191
    const int b  = t >> 8;
    const int r  = t & 255;
    const int u1 = r >> 4;            // c1 32-tile 0..15
    const int u2 = r & 15;            // c2 32-tile 0..15

    const __bf16* A  = xT1 + ((size_t)(b * CC + u1 * 32 + lo5) * KP + hi * 8);
    const __bf16* Bp = xT2 + ((size_t)(b * CC + u2 * 32 + lo5) * KP + hi * 8);

    f32x16 acc = {};
    bf8 Af[7], Bf[7];

    #pragma unroll
    for (int s = 0; s < 7; ++s) {
        Af[s] = *(const bf8*)(A  + s * 16);
        Bf[s] = *(const bf8*)(Bp + s * 16);
    }
    #pragma unroll
    for (int s = 0; s < 7; ++s)
        acc = __builtin_amdgcn_mfma_f32_32x32x16_bf16(Af[s], Bf[s], acc, 0, 0, 0);

    #pragma unroll
    for (int s = 0; s < 7; ++s) {
        Af[s] = *(const bf8*)(A  + (7 + s) * 16);
        Bf[s] = *(const bf8*)(Bp + (7 + s) * 16);
    }
    #pragma unroll
    for (int s = 0; s < 7; ++s)
        acc = __builtin_amdgcn_mfma_f32_32x32x16_bf16(Af[s], Bf[s], acc, 0, 0, 0);

    // flat store: G[b][c1][c2]; C/D: col=lane&31, row=(reg&3)+8*(reg>>2)+4*hi
    float* Gb = G + (size_t)b * (CC * CC);
    const int c2 = u2 * 32 + lo5;
    #pragma unroll
    for (int reg = 0; reg < 16; ++reg) {
        const int c1 = u1 * 32 + (reg & 3) + 8 * (reg >> 2) + 4 * hi;
        Gb[c1 * CC + c2] = acc[reg];
    }
}

// ---------- gather: out[b][d] = sum of G_b[list[k]] over bucket d ----------
__global__ __launch_bounds__(NTHR) void cbp_gather_kernel(
    const float* __restrict__ G, const unsigned int* __restrict__ list,
    const int* __restrict__ off, float* __restrict__ out)
{
    const int bid0 = blockIdx.x;                      // 0..1023
    const int swz  = (bid0 & 7) * 128 + (bid0 >> 3);  // same-b blocks -> same XCD
    const int b    = swz >> 5;                        // 0..31
    const int d    = (swz & 31) * 256 + threadIdx.x;  // bucket id

    const int o1 = off[d];
    const int o2 = off[d + 1];
    const float* Gb = G + (size_t)b * (CC * CC);

    float s = 0.0f;
    for (int k = o1; k < o2; ++k)
        s += Gb[list[k]];
    out[(size_t)b * DD + d] = s;
}

// ---------- fallback: R5/R4 proven fused kernel (fp32 inputs direct) ----------
__global__ __launch_bounds__(NTHR) void cbp_mfma_kernel(
    const float* __restrict__ x1, const float* __restrict__ x2,
    const float* __restrict__ s1, const float* __restrict__ s2,
    const int*   __restrict__ h1, const int*   __restrict__ h2,
    float* __restrict__ ws, float* __restrict__ out, int use_ws)
{
    __shared__ float accD[DD];
    const int bid  = blockIdx.x;
    const int b    = bid >> 4;
    const int t1   = (bid >> 2) & 3;
    const int t2   = bid & 3;
    const int tid  = threadIdx.x;
    const int wid  = tid >> 6;
    const int lane = tid & 63;
    const int wr   = wid >> 1;
    const int wc   = wid & 1;
    const int lo5  = lane & 31;
    const int hi   = lane >> 5;

    for (int i = tid; i < DD; i += NTHR) accD[i] = 0.0f;
    __syncthreads();

    const int c1w = t1 * 128 + wr * 64;
    const int c2w = t2 * 128 + wc * 64;
    const float* A0 = x1 + (size_t)b * HW * CC + (c1w + lo5);
    const float* A1 = A0 + 32;
    const float* B0 = x2 + (size_t)b * HW * CC + (c2w + lo5);
    const float* B1 = B0 + 32;

    f32x16 acc00 = {}, acc01 = {}, acc10 = {}, acc11 = {};
    for (int ks = 0; ks < 12; ++ks) {
        const int kb = ks * 16 + hi * 8;
        bf8 a0, a1, b0v, b1v;
        #pragma unroll
        for (int j = 0; j < 8; ++j) {
            const size_t offx = (size_t)(kb + j) * CC;
            a0[j] = (__bf16)A0[offx]; a1[j] = (__bf16)A1[offx];
            b0v[j] = (__bf16)B0[offx]; b1v[j] = (__bf16)B1[offx];
        }
        acc00 = __builtin_amdgcn_mfma_f32_32x32x16_bf16(a0, b0v, acc00, 0, 0, 0);
        acc01 = __builtin_amdgcn_mfma_f32_32x32x16_bf16(a0, b1v, acc01, 0, 0, 0);
        acc10 = __builtin_amdgcn_mfma_f32_32x32x16_bf16(a1, b0v, acc10, 0, 0, 0);
        acc11 = __builtin_amdgcn_mfma_f32_32x32x16_bf16(a1, b1v, acc11, 0, 0, 0);
    }
    {
        const int kb = 192 + hi * 8;
        bf8 a0, a1, b0v, b1v;
        #pragma unroll
        for (int j = 0; j < 8; ++j) {
            const int k = kb + j;
            const size_t offx = (size_t)k * CC;
            const bool v = (k < HW);
            a0[j]  = (__bf16)(v ? A0[offx] : 0.0f);
            a1[j]  = (__bf16)(v ? A1[offx] : 0.0f);
            b0v[j] = (__bf16)(v ? B0[offx] : 0.0f);
            b1v[j] = (__bf16)(v ? B1[offx] : 0.0f);
        }
        acc00 = __builtin_amdgcn_mfma_f32_32x32x16_bf16(a0, b0v, acc00, 0, 0, 0);
        acc01 = __builtin_amdgcn_mfma_f32_32x32x16_bf16(a0, b1v, acc01, 0, 0, 0);
        acc10 = __builtin_amdgcn_mfma_f32_32x32x16_bf16(a1, b0v, acc10, 0, 0, 0);
        acc11 = __builtin_amdgcn_mfma_f32_32x32x16_bf16(a1, b1v, acc11, 0, 0, 0);
    }

    const float s2v0 = s2[c2w + lo5];
    const float s2v1 = s2[c2w + 32 + lo5];
    const int   h2v0 = h2[c2w + lo5];
    const int   h2v1 = h2[c2w + 32 + lo5];
    #pragma unroll
    for (int rt = 0; rt < 2; ++rt) {
        const f32x16 accL = rt ? acc10 : acc00;
        const f32x16 accR = rt ? acc11 : acc01;
        #pragma unroll
        for (int reg = 0; reg < 16; ++reg) {
            const int c1 = c1w + rt * 32 + (reg & 3) + 8 * (reg >> 2) + 4 * hi;
            const float sv = s1[c1];
            const int   hv = h1[c1];
            unsafeAtomicAdd(&accD[(hv + h2v0) & (DD - 1)], sv * s2v0 * accL[reg]);
            unsafeAtomicAdd(&accD[(hv + h2v1) & (DD - 1)], sv * s2v1 * accR[reg]);
        }
    }
    __syncthreads();

    if (use_ws) {
        float4* dst = (float4*)(ws + (size_t)bid * DD);
        const float4* src = (const float4*)accD;
        #pragma unroll
        for (int i = 0; i < DD / 4 / NTHR; ++i)
            dst[tid + i * NTHR] = src[tid + i * NTHR];
    } else {
        float* ob = out + (size_t)b * DD;
        for (int i = tid; i < DD; i += NTHR)
            atomicAdd(&ob[i], accD[i]);
    }
}

__global__ __launch_bounds__(NTHR) void cbp_reduce_kernel(
    const float* __restrict__ parts, float* __restrict__ out)
{
    const int b  = blockIdx.x >> 3;
    const int d0 = (blockIdx.x & 7) * 1024 + threadIdx.x * 4;
    const float* base = parts + (size_t)b * TILES_PER_B * DD + d0;
    float4 sum = {0.f, 0.f, 0.f, 0.f};
    #pragma unroll
    for (int t = 0; t < TILES_PER_B; ++t) {
        float4 v = *(const float4*)(base + (size_t)t * DD);
        sum.x += v.x; sum.y += v.y; sum.z += v.z; sum.w += v.w;
    }
    *(float4*)(out + (size_t)b * DD + d0) = sum;
}

extern "C" void kernel_launch(void* const* d_in, const int* in_sizes, int n_in,
                              void* d_out, int out_size, void* d_ws, size_t ws_size,
                              hipStream_t stream) {
    const float* x1 = (const float*)d_in[0];
    const float* x2 = (const float*)d_in[1];
    const float* s1 = (const float*)d_in[2];
    const float* s2 = (const float*)d_in[3];
    const int*   h1 = (const int*)d_in[4];
    const int*   h2 = (const int*)d_in[5];
    float* out = (float*)d_out;
    char*  ws  = (char*)d_ws;

    dim3 block(NTHR);
    if (ws_size >= NEED_GATHER) {
        float*        G      = (float*)(ws + OFF_G);
        __bf16*       xT1    = (__bf16*)(ws + OFF_XT1);
        __bf16*       xT2    = (__bf16*)(ws + OFF_XT2);
        int*          cnt    = (int*)(ws + OFF_CNT);
        int*          cursor = (int*)(ws + OFF_CUR);
        int*          offb   = (int*)(ws + OFF_OFF);
        unsigned int* list   = (unsigned int*)(ws + OFF_LIST);

        // zero cnt + cursor (adjacent, 64 KB) — ws is poisoned each call
        hipMemsetAsync(cnt, 0, 65536, stream);

        cbp_transpose_kernel<<<dim3(NB * 32), block, 0, stream>>>(
            x1, x2, s1, s2, xT1, xT2);
        cbp_hist_kernel<<<dim3(256), block, 0, stream>>>(h1, h2, cnt);
        cbp_scan_kernel<<<dim3(1), block, 0, stream>>>(cnt, offb);
        cbp_fill_kernel<<<dim3(256), block, 0, stream>>>(h1, h2, offb, cursor, list);
        cbp_gram_flat_kernel<<<dim3(2048), block, 0, stream>>>(xT1, xT2, G);
        cbp_gather_kernel<<<dim3(1024), block, 0, stream>>>(G, list, offb, out);
    } else if (ws_size >= NEED_R5) {
        float* parts = (float*)d_ws;
        cbp_mfma_kernel<<<dim3(NB * TILES_PER_B), block, 0, stream>>>(
            x1, x2, s1, s2, h1, h2, parts, out, 1);
        cbp_reduce_kernel<<<dim3(NB * 8), block, 0, stream>>>(parts, out);
    } else {
        hipMemsetAsync(out, 0, (size_t)out_size * sizeof(float), stream);
        cbp_mfma_kernel<<<dim3(NB * TILES_PER_B), block, 0, stream>>>(
            x1, x2, s1, s2, h1, h2, (float*)d_ws, out, 0);
    }
}